// Round 6
// baseline (197.560 us; speedup 1.0000x reference)
//
#include <hip/hip_runtime.h>

#define CIN   32
#define COUT  64
#define K_OFF 27

typedef __attribute__((ext_vector_type(8))) short bf16x8;
typedef __attribute__((ext_vector_type(4))) float f32x4;

__device__ inline unsigned short f2bf_rne(float f) {
    union { float f; unsigned int u; } v; v.f = f;
    unsigned int u = v.u;
    u = (u + 0x7fffu + ((u >> 16) & 1u)) >> 16;
    return (unsigned short)u;
}

// ---------------------------------------------------------------------------
// Prep (single launch): [0,Bf) feat fp32->bf16 | [Bf,Bf+Bw) weights ->
// fragment-order bf16 wt2[k][ct][lane][8] | last block: mask-dtype detect
// (any nonzero byte at offset %4!=0 in first 4KB => 1-byte bool, flag=1).
// ---------------------------------------------------------------------------
__global__ __launch_bounds__(256) void prep_kernel(
    const float* __restrict__ feat, const float* __restrict__ wk,
    const unsigned char* __restrict__ maskb,
    unsigned short* __restrict__ featb, unsigned short* __restrict__ wt2,
    int* __restrict__ flag, int n, int Bf, int Bw, int det_bytes)
{
    const int gid = blockIdx.x;
    if (gid < Bf) {
        const int base = (gid * 256 + threadIdx.x) * 8;
        if (base < n * CIN) {
            float4 a = *(const float4*)(feat + base);
            float4 b = *(const float4*)(feat + base + 4);
            bf16x8 v;
            v[0] = (short)f2bf_rne(a.x); v[1] = (short)f2bf_rne(a.y);
            v[2] = (short)f2bf_rne(a.z); v[3] = (short)f2bf_rne(a.w);
            v[4] = (short)f2bf_rne(b.x); v[5] = (short)f2bf_rne(b.y);
            v[6] = (short)f2bf_rne(b.z); v[7] = (short)f2bf_rne(b.w);
            *(bf16x8*)(featb + base) = v;
        }
    } else if (gid < Bf + Bw) {
        const int t = (gid - Bf) * 256 + threadIdx.x;   // fragment slot id
        if (t < K_OFF * 4 * 64) {
            const int lane = t & 63, ct = (t >> 6) & 3, k = t >> 8;
            const int lrow = lane & 15, q = lane >> 4;
            const int col = ct * 16 + lrow;
            bf16x8 v;
            #pragma unroll
            for (int j = 0; j < 8; ++j)
                v[j] = (short)f2bf_rne(wk[(k * CIN + q * 8 + j) * COUT + col]);
            *(bf16x8*)(wt2 + t * 8) = v;
        }
    } else {
        __shared__ int wany[4];
        int found = 0;
        for (int i = threadIdx.x; i < det_bytes; i += 256)
            if ((i & 3) && maskb[i]) found = 1;
        unsigned long long b = __ballot(found);
        if ((threadIdx.x & 63) == 0) wany[threadIdx.x >> 6] = b ? 1 : 0;
        __syncthreads();
        if (threadIdx.x == 0) *flag = wany[0] | wany[1] | wany[2] | wany[3];
    }
}

// ---------------------------------------------------------------------------
// Main MFMA kernel — round-3 structure (proven 62us), with:
//   - __launch_bounds__(256,4): VGPR cap 128 so the declared pipeline
//     (~117 VGPR) stays in registers (round-3 VGPR=64 => collapsed), and
//     no spill risk (round-5's 168-cap + deeper pipeline crashed).
//   - single-path mask read: byte pointer + mshift (bool:0 / int32:2).
// Barrier-free, no LDS. Block = 4 waves; wave owns 32 rows x 64 couts
// (2 row-frags x 4 col-frags, 8 MFMA/iter).
// Pipeline: midx +3 (2 slots), gathers +2 (3 slots), B +1 (2 slots).
// ---------------------------------------------------------------------------
__global__ __launch_bounds__(256, 4) void conv_mfma6(
    const unsigned short* __restrict__ featb,   // [N][CIN] bf16
    const int*            __restrict__ nmap,    // [K][N]
    const unsigned char*  __restrict__ maskb,   // byte view of mask
    const unsigned short* __restrict__ wt2,     // fragment-order weights
    float* __restrict__ out, int n, const int* __restrict__ flag)
{
    const int tid  = threadIdx.x;
    const int wave = tid >> 6;
    const int lane = tid & 63;
    const int lrow = lane & 15;
    const int q    = lane >> 4;
    const int n0   = blockIdx.x * 128 + wave * 32;
    const int mshift = (*flag) ? 0 : 2;

    const int  row0 = n0 + lrow, row1 = n0 + 16 + lrow;
    const bool vr0 = row0 < n, vr1 = row1 < n;

    auto load_mi = [&](int k, int rt) -> int {
        const int  r = rt ? row1 : row0;
        const bool v = rt ? vr1 : vr0;
        if (!v) return -1;
        const int idx = k * n + r;
        const unsigned char mv = maskb[(size_t)idx << mshift];
        const int nm = nmap[idx];
        return mv ? nm : -1;
    };
    auto gather = [&](int mi) -> bf16x8 {
        bf16x8 z = {0, 0, 0, 0, 0, 0, 0, 0};
        if (mi >= 0) z = *(const bf16x8*)(featb + (size_t)mi * CIN + q * 8);
        return z;
    };
    auto loadB = [&](int k, bf16x8* dst) {
        const unsigned short* p = wt2 + ((k * 4) << 9) + lane * 8;
        #pragma unroll
        for (int ct = 0; ct < 4; ++ct) dst[ct] = *(const bf16x8*)(p + (ct << 9));
    };

    int    mi_buf[2][2];
    bf16x8 a_buf[3][2];
    bf16x8 B_buf[2][4];
    f32x4  acc[2][4] = {};

    // prologue: a[0], a[1] gathered; mi for offset 2 in slot 0; B[0] loaded
    {
        int t0 = load_mi(0, 0), t1 = load_mi(0, 1);
        int u0 = load_mi(1, 0), u1 = load_mi(1, 1);
        mi_buf[0][0] = load_mi(2, 0);
        mi_buf[0][1] = load_mi(2, 1);
        loadB(0, B_buf[0]);
        a_buf[0][0] = gather(t0); a_buf[0][1] = gather(t1);
        a_buf[1][0] = gather(u0); a_buf[1][1] = gather(u1);
    }

    #pragma unroll
    for (int k = 0; k < K_OFF; ++k) {
        if (k + 3 < K_OFF) {                      // midx[k+3] -> slot (k+1)&1
            mi_buf[(k + 1) & 1][0] = load_mi(k + 3, 0);
            mi_buf[(k + 1) & 1][1] = load_mi(k + 3, 1);
        }
        if (k + 2 < K_OFF) {                      // a[k+2] from midx slot k&1
            a_buf[(k + 2) % 3][0] = gather(mi_buf[k & 1][0]);
            a_buf[(k + 2) % 3][1] = gather(mi_buf[k & 1][1]);
        }
        if (k + 1 < K_OFF) loadB(k + 1, B_buf[(k + 1) & 1]);

        const int s = k % 3, bs = k & 1;
        #pragma unroll
        for (int ct = 0; ct < 4; ++ct) {
            acc[0][ct] = __builtin_amdgcn_mfma_f32_16x16x32_bf16(
                a_buf[s][0], B_buf[bs][ct], acc[0][ct], 0, 0, 0);
            acc[1][ct] = __builtin_amdgcn_mfma_f32_16x16x32_bf16(
                a_buf[s][1], B_buf[bs][ct], acc[1][ct], 0, 0, 0);
        }
    }

    // epilogue: C/D layout col=lane&15, row=q*4+reg
    #pragma unroll
    for (int rt = 0; rt < 2; ++rt)
        #pragma unroll
        for (int ct = 0; ct < 4; ++ct)
            #pragma unroll
            for (int r = 0; r < 4; ++r) {
                const int row = n0 + rt * 16 + q * 4 + r;
                if (row < n) out[(size_t)row * COUT + ct * 16 + lrow] = acc[rt][ct][r];
            }
}

// ---------------------------------------------------------------------------
// fp32 fallback path (only if ws too small for bf16 staging).
// ---------------------------------------------------------------------------
__global__ __launch_bounds__(256) void detect_mask(
    const unsigned char* __restrict__ mask, int nbytes, int* __restrict__ flag) {
    __shared__ int wany[4];
    int found = 0;
    for (int i = threadIdx.x; i < nbytes; i += 256)
        if ((i & 3) && mask[i]) found = 1;
    unsigned long long b = __ballot(found);
    if ((threadIdx.x & 63) == 0) wany[threadIdx.x >> 6] = b ? 1 : 0;
    __syncthreads();
    if (threadIdx.x == 0) *flag = wany[0] | wany[1] | wany[2] | wany[3];
}

#define BN 64
__global__ __launch_bounds__(256) void sparse_conv_fp32(
    const float* __restrict__ feat, const int* __restrict__ nmap,
    const unsigned char* __restrict__ mask8, const int* __restrict__ mask32,
    const float* __restrict__ wk, float* __restrict__ out,
    int n, const int* __restrict__ flag)
{
    __shared__ float A[CIN][BN];
    __shared__ float W[CIN][COUT];
    const int tid = threadIdx.x;
    const int n0 = blockIdx.x * BN;
    const int is_b8 = *flag;
    const int r0 = (tid >> 4) * 4, c0 = (tid & 15) * 4;
    const int grow = tid >> 2, gpart = tid & 3;
    float acc[4][4] = {};
    for (int k = 0; k < K_OFF; ++k) {
        {
            const int base = tid * 8;
            const float* wsrc = wk + (size_t)k * (CIN * COUT) + base;
            float4 w0 = ((const float4*)wsrc)[0];
            float4 w1 = ((const float4*)wsrc)[1];
            *(float4*)&W[base >> 6][base & 63] = w0;
            *(float4*)&W[base >> 6][(base & 63) + 4] = w1;
        }
        {
            const int gn = n0 + grow;
            float4 f0 = make_float4(0.f, 0.f, 0.f, 0.f), f1 = f0;
            if (gn < n) {
                const int idx = k * n + gn;
                const int m = is_b8 ? (int)mask8[idx] : mask32[idx];
                if (m) {
                    const float* fsrc = feat + (size_t)nmap[idx] * CIN + gpart * 8;
                    f0 = ((const float4*)fsrc)[0];
                    f1 = ((const float4*)fsrc)[1];
                }
            }
            const int cb = gpart * 8;
            A[cb+0][grow]=f0.x; A[cb+1][grow]=f0.y; A[cb+2][grow]=f0.z; A[cb+3][grow]=f0.w;
            A[cb+4][grow]=f1.x; A[cb+5][grow]=f1.y; A[cb+6][grow]=f1.z; A[cb+7][grow]=f1.w;
        }
        __syncthreads();
        #pragma unroll
        for (int c = 0; c < CIN; ++c) {
            const float4 a = *(const float4*)&A[c][r0];
            const float4 w = *(const float4*)&W[c][c0];
            acc[0][0]+=a.x*w.x; acc[0][1]+=a.x*w.y; acc[0][2]+=a.x*w.z; acc[0][3]+=a.x*w.w;
            acc[1][0]+=a.y*w.x; acc[1][1]+=a.y*w.y; acc[1][2]+=a.y*w.z; acc[1][3]+=a.y*w.w;
            acc[2][0]+=a.z*w.x; acc[2][1]+=a.z*w.y; acc[2][2]+=a.z*w.z; acc[2][3]+=a.z*w.w;
            acc[3][0]+=a.w*w.x; acc[3][1]+=a.w*w.y; acc[3][2]+=a.w*w.z; acc[3][3]+=a.w*w.w;
        }
        __syncthreads();
    }
    #pragma unroll
    for (int i = 0; i < 4; ++i) {
        const int orow = n0 + r0 + i;
        if (orow < n)
            *(float4*)&out[(size_t)orow * COUT + c0] =
                make_float4(acc[i][0], acc[i][1], acc[i][2], acc[i][3]);
    }
}

static inline size_t align16(size_t x) { return (x + 15) & ~(size_t)15; }

extern "C" void kernel_launch(void* const* d_in, const int* in_sizes, int n_in,
                              void* d_out, int out_size, void* d_ws, size_t ws_size,
                              hipStream_t stream) {
    const float*         feat = (const float*)d_in[0];
    const int*           nmap = (const int*)d_in[1];
    const unsigned char* m8   = (const unsigned char*)d_in[2];
    const int*           m32  = (const int*)d_in[2];
    const float*         wk   = (const float*)d_in[3];
    float*               out  = (float*)d_out;

    const int n = in_sizes[0] / CIN;
    int* flag = (int*)d_ws;

    const size_t feat_off   = 128;
    const size_t feat_bytes = (size_t)n * CIN * 2;
    const size_t wt2_off    = align16(feat_off + feat_bytes);
    const size_t wt2_bytes  = (size_t)K_OFF * 4 * 64 * 8 * 2;
    const size_t needed     = wt2_off + wt2_bytes;

    const int mask_elems = K_OFF * n;
    const int det_bytes  = mask_elems < 4096 ? mask_elems : 4096;

    if (ws_size >= needed) {
        unsigned short* featb = (unsigned short*)((char*)d_ws + feat_off);
        unsigned short* wt2   = (unsigned short*)((char*)d_ws + wt2_off);
        const int Bf = (n * CIN / 8 + 255) / 256;
        const int Bw = (K_OFF * 4 * 64 + 255) / 256;
        prep_kernel<<<Bf + Bw + 1, 256, 0, stream>>>(
            feat, wk, m8, featb, wt2, flag, n, Bf, Bw, det_bytes);
        const int nblocks = (n + 127) / 128;
        conv_mfma6<<<nblocks, 256, 0, stream>>>(featb, nmap, m8, wt2, out, n, flag);
    } else {
        detect_mask<<<1, 256, 0, stream>>>(m8, det_bytes, flag);
        const int nb = (n + BN - 1) / BN;
        sparse_conv_fp32<<<nb, 256, 0, stream>>>(feat, nmap, m8, m32, wk, out, n, flag);
    }
}

// Round 7
// 176.663 us; speedup vs baseline: 1.1183x; 1.1183x over previous
//
#include <hip/hip_runtime.h>

#define CIN   32
#define COUT  64
#define K_OFF 27

typedef __attribute__((ext_vector_type(8))) short bf16x8;
typedef __attribute__((ext_vector_type(4))) float f32x4;

__device__ inline unsigned short f2bf_rne(float f) {
    union { float f; unsigned int u; } v; v.f = f;
    unsigned int u = v.u;
    u = (u + 0x7fffu + ((u >> 16) & 1u)) >> 16;
    return (unsigned short)u;
}

// ---------------------------------------------------------------------------
// Mask-dtype detect (single small block): any nonzero byte at offset %4 != 0
// in the first 4KB => 1-byte bool (flag=1), else int32 (flag=0).
// ---------------------------------------------------------------------------
__global__ __launch_bounds__(256) void detect_mask(
    const unsigned char* __restrict__ mask, int nbytes, int* __restrict__ flag) {
    __shared__ int wany[4];
    int found = 0;
    for (int i = threadIdx.x; i < nbytes; i += 256)
        if ((i & 3) && mask[i]) found = 1;
    unsigned long long b = __ballot(found);
    if ((threadIdx.x & 63) == 0) wany[threadIdx.x >> 6] = b ? 1 : 0;
    __syncthreads();
    if (threadIdx.x == 0) *flag = wany[0] | wany[1] | wany[2] | wany[3];
}

// ---------------------------------------------------------------------------
// Fused prep (runs after detect on same stream):
//   [0,Bf)        feat fp32 -> bf16
//   [Bf,Bf+Bm)    midx = mask ? nmap : -1   (one fused dword per entry)
//   [Bf+Bm,..)    weights -> fragment-order bf16 wt2[k][ct][lane][8]
// ---------------------------------------------------------------------------
__global__ __launch_bounds__(256) void prep_kernel(
    const float* __restrict__ feat, const int* __restrict__ nmap,
    const unsigned char* __restrict__ mask8, const int* __restrict__ mask32,
    const float* __restrict__ wk,
    unsigned short* __restrict__ featb, int* __restrict__ midx,
    unsigned short* __restrict__ wt2,
    int n, int Bf, int Bm, const int* __restrict__ flag)
{
    const int gid = blockIdx.x;
    if (gid < Bf) {
        const int base = (gid * 256 + threadIdx.x) * 8;
        if (base < n * CIN) {
            float4 a = *(const float4*)(feat + base);
            float4 b = *(const float4*)(feat + base + 4);
            bf16x8 v;
            v[0] = (short)f2bf_rne(a.x); v[1] = (short)f2bf_rne(a.y);
            v[2] = (short)f2bf_rne(a.z); v[3] = (short)f2bf_rne(a.w);
            v[4] = (short)f2bf_rne(b.x); v[5] = (short)f2bf_rne(b.y);
            v[6] = (short)f2bf_rne(b.z); v[7] = (short)f2bf_rne(b.w);
            *(bf16x8*)(featb + base) = v;
        }
    } else if (gid < Bf + Bm) {
        const int t = (gid - Bf) * 256 + threadIdx.x;
        int i = t * 4;
        const int total = K_OFF * n;
        const int is_b8 = *flag;
        if (i + 3 < total) {
            int4 nm = *(const int4*)(nmap + i);
            int m0, m1, m2, m3;
            if (is_b8) {
                uchar4 mb = *(const uchar4*)(mask8 + i);
                m0 = mb.x; m1 = mb.y; m2 = mb.z; m3 = mb.w;
            } else {
                int4 mm = *(const int4*)(mask32 + i);
                m0 = mm.x; m1 = mm.y; m2 = mm.z; m3 = mm.w;
            }
            int4 r;
            r.x = m0 ? nm.x : -1; r.y = m1 ? nm.y : -1;
            r.z = m2 ? nm.z : -1; r.w = m3 ? nm.w : -1;
            *(int4*)(midx + i) = r;
        } else {
            for (; i < total; ++i) {
                int m = is_b8 ? (int)mask8[i] : mask32[i];
                midx[i] = m ? nmap[i] : -1;
            }
        }
    } else {
        const int t = (gid - Bf - Bm) * 256 + threadIdx.x;  // fragment id
        if (t < K_OFF * 4 * 64) {
            const int lane = t & 63, ct = (t >> 6) & 3, k = t >> 8;
            const int lrow = lane & 15, q = lane >> 4;
            const int col = ct * 16 + lrow;
            bf16x8 v;
            #pragma unroll
            for (int j = 0; j < 8; ++j)
                v[j] = (short)f2bf_rne(wk[(k * CIN + q * 8 + j) * COUT + col]);
            *(bf16x8*)(wt2 + t * 8) = v;
        }
    }
}

// ---------------------------------------------------------------------------
// Main MFMA kernel — round-3 structure VERBATIM (proven 62us, passed), with
// ONE change: amdgpu_waves_per_eu(3,4). The max=4 clamps the scheduler's
// occupancy target so it stops collapsing the software pipeline to chase
// 8 waves/EU (R3 emitted VGPR=64, R6's launch_bounds floor gave 52 — both
// collapsed the declared ~117-VGPR pipeline). Floor 3 keeps spill risk nil.
// Barrier-free, no LDS. Wave = 32 rows x 64 couts, 8 MFMA/iter.
// Pipeline: midx +3 (2 slots), gathers +2 (3 slots), B +1 (2 slots).
// ---------------------------------------------------------------------------
__global__ __attribute__((amdgpu_waves_per_eu(3, 4))) __launch_bounds__(256)
void conv_mfma7(
    const unsigned short* __restrict__ featb,   // [N][CIN] bf16
    const int*            __restrict__ midx,    // [K][N] fused mask?nmap:-1
    const unsigned short* __restrict__ wt2,     // fragment-order weights
    float* __restrict__ out, int n)
{
    const int tid  = threadIdx.x;
    const int wave = tid >> 6;
    const int lane = tid & 63;
    const int lrow = lane & 15;
    const int q    = lane >> 4;
    const int n0   = blockIdx.x * 128 + wave * 32;

    const int  row0 = n0 + lrow, row1 = n0 + 16 + lrow;
    const bool vr0 = row0 < n, vr1 = row1 < n;

    auto load_mi = [&](int k, int rt) -> int {
        const int  r = rt ? row1 : row0;
        const bool v = rt ? vr1 : vr0;
        if (!v) return -1;
        return midx[k * n + r];
    };
    auto gather = [&](int mi) -> bf16x8 {
        bf16x8 z = {0, 0, 0, 0, 0, 0, 0, 0};
        if (mi >= 0) z = *(const bf16x8*)(featb + (size_t)mi * CIN + q * 8);
        return z;
    };
    auto loadB = [&](int k, bf16x8* dst) {
        const unsigned short* p = wt2 + ((k * 4) << 9) + lane * 8;
        #pragma unroll
        for (int ct = 0; ct < 4; ++ct) dst[ct] = *(const bf16x8*)(p + (ct << 9));
    };

    int    mi_buf[2][2];
    bf16x8 a_buf[3][2];
    bf16x8 B_buf[2][4];
    f32x4  acc[2][4] = {};

    // prologue: a[0], a[1] gathered; midx for offset 2 in slot 0; B[0] loaded
    {
        int t0 = load_mi(0, 0), t1 = load_mi(0, 1);
        int u0 = load_mi(1, 0), u1 = load_mi(1, 1);
        mi_buf[0][0] = load_mi(2, 0);
        mi_buf[0][1] = load_mi(2, 1);
        a_buf[0][0] = gather(t0); a_buf[0][1] = gather(t1);
        a_buf[1][0] = gather(u0); a_buf[1][1] = gather(u1);
        loadB(0, B_buf[0]);
    }

    #pragma unroll
    for (int k = 0; k < K_OFF; ++k) {
        if (k + 3 < K_OFF) {                      // midx[k+3] -> slot (k+1)&1
            mi_buf[(k + 1) & 1][0] = load_mi(k + 3, 0);
            mi_buf[(k + 1) & 1][1] = load_mi(k + 3, 1);
        }
        if (k + 2 < K_OFF) {                      // a[k+2] from midx slot k&1
            a_buf[(k + 2) % 3][0] = gather(mi_buf[k & 1][0]);
            a_buf[(k + 2) % 3][1] = gather(mi_buf[k & 1][1]);
        }
        if (k + 1 < K_OFF) loadB(k + 1, B_buf[(k + 1) & 1]);

        const int s = k % 3, bs = k & 1;
        #pragma unroll
        for (int ct = 0; ct < 4; ++ct) {
            acc[0][ct] = __builtin_amdgcn_mfma_f32_16x16x32_bf16(
                a_buf[s][0], B_buf[bs][ct], acc[0][ct], 0, 0, 0);
            acc[1][ct] = __builtin_amdgcn_mfma_f32_16x16x32_bf16(
                a_buf[s][1], B_buf[bs][ct], acc[1][ct], 0, 0, 0);
        }
    }

    // epilogue: C/D layout col=lane&15, row=q*4+reg
    #pragma unroll
    for (int rt = 0; rt < 2; ++rt)
        #pragma unroll
        for (int ct = 0; ct < 4; ++ct)
            #pragma unroll
            for (int r = 0; r < 4; ++r) {
                const int row = n0 + rt * 16 + q * 4 + r;
                if (row < n) out[(size_t)row * COUT + ct * 16 + lrow] = acc[rt][ct][r];
            }
}

// ---------------------------------------------------------------------------
// fp32 fallback path (only if ws too small for bf16 staging).
// ---------------------------------------------------------------------------
#define BN 64
__global__ __launch_bounds__(256) void sparse_conv_fp32(
    const float* __restrict__ feat, const int* __restrict__ nmap,
    const unsigned char* __restrict__ mask8, const int* __restrict__ mask32,
    const float* __restrict__ wk, float* __restrict__ out,
    int n, const int* __restrict__ flag)
{
    __shared__ float A[CIN][BN];
    __shared__ float W[CIN][COUT];
    const int tid = threadIdx.x;
    const int n0 = blockIdx.x * BN;
    const int is_b8 = *flag;
    const int r0 = (tid >> 4) * 4, c0 = (tid & 15) * 4;
    const int grow = tid >> 2, gpart = tid & 3;
    float acc[4][4] = {};
    for (int k = 0; k < K_OFF; ++k) {
        {
            const int base = tid * 8;
            const float* wsrc = wk + (size_t)k * (CIN * COUT) + base;
            float4 w0 = ((const float4*)wsrc)[0];
            float4 w1 = ((const float4*)wsrc)[1];
            *(float4*)&W[base >> 6][base & 63] = w0;
            *(float4*)&W[base >> 6][(base & 63) + 4] = w1;
        }
        {
            const int gn = n0 + grow;
            float4 f0 = make_float4(0.f, 0.f, 0.f, 0.f), f1 = f0;
            if (gn < n) {
                const int idx = k * n + gn;
                const int m = is_b8 ? (int)mask8[idx] : mask32[idx];
                if (m) {
                    const float* fsrc = feat + (size_t)nmap[idx] * CIN + gpart * 8;
                    f0 = ((const float4*)fsrc)[0];
                    f1 = ((const float4*)fsrc)[1];
                }
            }
            const int cb = gpart * 8;
            A[cb+0][grow]=f0.x; A[cb+1][grow]=f0.y; A[cb+2][grow]=f0.z; A[cb+3][grow]=f0.w;
            A[cb+4][grow]=f1.x; A[cb+5][grow]=f1.y; A[cb+6][grow]=f1.z; A[cb+7][grow]=f1.w;
        }
        __syncthreads();
        #pragma unroll
        for (int c = 0; c < CIN; ++c) {
            const float4 a = *(const float4*)&A[c][r0];
            const float4 w = *(const float4*)&W[c][c0];
            acc[0][0]+=a.x*w.x; acc[0][1]+=a.x*w.y; acc[0][2]+=a.x*w.z; acc[0][3]+=a.x*w.w;
            acc[1][0]+=a.y*w.x; acc[1][1]+=a.y*w.y; acc[1][2]+=a.y*w.z; acc[1][3]+=a.y*w.w;
            acc[2][0]+=a.z*w.x; acc[2][1]+=a.z*w.y; acc[2][2]+=a.z*w.z; acc[2][3]+=a.z*w.w;
            acc[3][0]+=a.w*w.x; acc[3][1]+=a.w*w.y; acc[3][2]+=a.w*w.z; acc[3][3]+=a.w*w.w;
        }
        __syncthreads();
    }
    #pragma unroll
    for (int i = 0; i < 4; ++i) {
        const int orow = n0 + r0 + i;
        if (orow < n)
            *(float4*)&out[(size_t)orow * COUT + c0] =
                make_float4(acc[i][0], acc[i][1], acc[i][2], acc[i][3]);
    }
}

static inline size_t align16(size_t x) { return (x + 15) & ~(size_t)15; }

extern "C" void kernel_launch(void* const* d_in, const int* in_sizes, int n_in,
                              void* d_out, int out_size, void* d_ws, size_t ws_size,
                              hipStream_t stream) {
    const float*         feat = (const float*)d_in[0];
    const int*           nmap = (const int*)d_in[1];
    const unsigned char* m8   = (const unsigned char*)d_in[2];
    const int*           m32  = (const int*)d_in[2];
    const float*         wk   = (const float*)d_in[3];
    float*               out  = (float*)d_out;

    const int n = in_sizes[0] / CIN;
    int* flag = (int*)d_ws;

    const size_t feat_off   = 128;
    const size_t feat_bytes = (size_t)n * CIN * 2;
    const size_t midx_off   = align16(feat_off + feat_bytes);
    const size_t midx_bytes = (size_t)K_OFF * n * 4;
    const size_t wt2_off    = align16(midx_off + midx_bytes);
    const size_t wt2_bytes  = (size_t)K_OFF * 4 * 64 * 8 * 2;
    const size_t needed     = wt2_off + wt2_bytes;

    const int mask_elems = K_OFF * n;
    const int det_bytes  = mask_elems < 4096 ? mask_elems : 4096;
    detect_mask<<<1, 256, 0, stream>>>(m8, det_bytes, flag);

    if (ws_size >= needed) {
        unsigned short* featb = (unsigned short*)((char*)d_ws + feat_off);
        int*            midx  = (int*)((char*)d_ws + midx_off);
        unsigned short* wt2   = (unsigned short*)((char*)d_ws + wt2_off);
        const int Bf = (n * CIN / 8 + 255) / 256;
        const int Bm = ((K_OFF * n + 3) / 4 + 255) / 256;
        const int Bw = (K_OFF * 4 * 64 + 255) / 256;
        prep_kernel<<<Bf + Bm + Bw, 256, 0, stream>>>(
            feat, nmap, m8, m32, wk, featb, midx, wt2, n, Bf, Bm, flag);
        const int nblocks = (n + 127) / 128;
        conv_mfma7<<<nblocks, 256, 0, stream>>>(featb, midx, wt2, out, n);
    } else {
        const int nb = (n + BN - 1) / BN;
        sparse_conv_fp32<<<nb, 256, 0, stream>>>(feat, nmap, m8, m32, wk, out, n, flag);
    }
}